// Round 1
// baseline (3365.184 us; speedup 1.0000x reference)
//
#include <hip/hip_runtime.h>
#include <math.h>

#define FIN  1433
#define HID  67
#define HIDP 68
#define NC   7
#define NCP  8

// ---------------- CSR build ----------------

__global__ void k_zero(int* __restrict__ cnt, int N) {
    int i = blockIdx.x * 256 + threadIdx.x;
    if (i < N) cnt[i] = 0;
}

__global__ void k_count(const int* __restrict__ dst, int* __restrict__ cnt, int E) {
    int e = blockIdx.x * 256 + threadIdx.x;
    if (e < E) atomicAdd(&cnt[dst[e]], 1);
}

__global__ void k_bsum(const int* __restrict__ cnt, int* __restrict__ bsum, int N) {
    __shared__ int s[256];
    int t = threadIdx.x;
    int i = blockIdx.x * 256 + t;
    s[t] = (i < N) ? cnt[i] : 0;
    __syncthreads();
    for (int o = 128; o > 0; o >>= 1) {
        if (t < o) s[t] += s[t + o];
        __syncthreads();
    }
    if (t == 0) bsum[blockIdx.x] = s[0];
}

// exclusive scan of block sums; nb <= 512
__global__ void k_scanb(int* __restrict__ bsum, int nb) {
    __shared__ int s[512];
    int t = threadIdx.x;
    int v = (t < nb) ? bsum[t] : 0;
    s[t] = v;
    __syncthreads();
    for (int o = 1; o < 512; o <<= 1) {
        int tmp = (t >= o) ? s[t - o] : 0;
        __syncthreads();
        s[t] += tmp;
        __syncthreads();
    }
    if (t < nb) bsum[t] = s[t] - v;  // exclusive
}

__global__ void k_scan3(const int* __restrict__ cnt, const int* __restrict__ bsum,
                        int* __restrict__ rowptr, int* __restrict__ cursor,
                        float* __restrict__ dinv, int N, int E) {
    __shared__ int s[256];
    int t = threadIdx.x;
    int i = blockIdx.x * 256 + t;
    int v = (i < N) ? cnt[i] : 0;
    s[t] = v;
    __syncthreads();
    for (int o = 1; o < 256; o <<= 1) {
        int tmp = (t >= o) ? s[t - o] : 0;
        __syncthreads();
        s[t] += tmp;
        __syncthreads();
    }
    if (i < N) {
        int start = bsum[blockIdx.x] + s[t] - v;  // exclusive global prefix
        rowptr[i] = start;
        cursor[i] = start;
        dinv[i]   = rsqrtf((float)(v + 1));       // +1 self loop; deg>=1 always
    }
    if (i == 0) rowptr[N] = E;
}

__global__ void k_fill(const int* __restrict__ ei, int* __restrict__ cursor,
                       int* __restrict__ csrs, int E) {
    int e = blockIdx.x * 256 + threadIdx.x;
    if (e < E) {
        int s = ei[e];          // source
        int d = ei[E + e];      // target
        int pos = atomicAdd(&cursor[d], 1);
        csrs[pos] = s;
    }
}

// ---------------- GEMM1: h1[N,68] = x[N,1433] @ W1[1433,67], col 67 zero-padded ----

__global__ __launch_bounds__(256) void k_gemm1(const float* __restrict__ x,
                                               const float* __restrict__ W1,
                                               float* __restrict__ h1, int N) {
    __shared__ float xs[32][260];   // [kk][r], pad 260 kills write conflicts (4-way, free-ish)
    __shared__ float wt[HIDP][32];  // [col][kk]
    int t  = threadIdx.x;
    int rg = t & 63;       // row group: rows 4*rg .. 4*rg+3
    int g  = t >> 6;       // wave id = col phase: cols g + 4*j
    int row0 = blockIdx.x << 8;

    float acc[4][17];
#pragma unroll
    for (int i = 0; i < 4; i++)
#pragma unroll
        for (int j = 0; j < 17; j++) acc[i][j] = 0.f;

    for (int kt = 0; kt < FIN; kt += 32) {
        // stage x tile: coalesced dword loads (1433-row stride is not 16B aligned)
#pragma unroll
        for (int q = 0; q < 32; q++) {
            int idx = q * 256 + t;
            int r  = idx >> 5;
            int kk = idx & 31;
            int grow = row0 + r;
            int k = kt + kk;
            float v = 0.f;
            if (grow < N && k < FIN) v = x[(long long)grow * FIN + k];
            xs[kk][r] = v;
        }
        // stage W tile (L2-hot after first blocks)
        for (int idx = t; idx < HIDP * 32; idx += 256) {
            int col = idx >> 5;
            int kk  = idx & 31;
            int k = kt + kk;
            float v = 0.f;
            if (col < HID && k < FIN) v = W1[k * HID + col];
            wt[col][kk] = v;
        }
        __syncthreads();
#pragma unroll
        for (int kc = 0; kc < 8; kc++) {
            float4 w4[17];
#pragma unroll
            for (int j = 0; j < 17; j++)
                w4[j] = *(const float4*)&wt[g + 4 * j][kc * 4];   // wave-uniform broadcast
#pragma unroll
            for (int c = 0; c < 4; c++) {
                const float4 a = *(const float4*)&xs[kc * 4 + c][rg * 4];  // contiguous b128
#pragma unroll
                for (int j = 0; j < 17; j++) {
                    float wv = ((const float*)&w4[j])[c];
                    acc[0][j] = fmaf(a.x, wv, acc[0][j]);
                    acc[1][j] = fmaf(a.y, wv, acc[1][j]);
                    acc[2][j] = fmaf(a.z, wv, acc[2][j]);
                    acc[3][j] = fmaf(a.w, wv, acc[3][j]);
                }
            }
        }
        __syncthreads();
    }
#pragma unroll
    for (int i = 0; i < 4; i++) {
        int row = row0 + rg * 4 + i;
        if (row < N) {
#pragma unroll
            for (int j = 0; j < 17; j++)
                h1[(long long)row * HIDP + g + 4 * j] = acc[i][j];
        }
    }
}

// ---------------- agg1: out1 = lrelu(b1 + dinv_d^2*h1_d + dinv_d * sum_e dinv_s*h1_s) ----

__global__ __launch_bounds__(256) void k_agg1(const float* __restrict__ h1,
                                              const int* __restrict__ rowptr,
                                              const int* __restrict__ csrs,
                                              const float* __restrict__ dinv,
                                              const float* __restrict__ b1,
                                              float* __restrict__ out1, int N) {
    int lane = threadIdx.x & 63;
    int d = blockIdx.x * 4 + (threadIdx.x >> 6);   // wave per node
    if (d >= N) return;
    int start = rowptr[d];
    int end   = rowptr[d + 1];
    float dd = dinv[d];
    float acc0 = 0.f, acc1 = 0.f;
    for (int e = start; e < end; e++) {
        int s = csrs[e];                 // wave-uniform -> broadcast load
        float w = dinv[s];
        const float* hp = h1 + (long long)s * HIDP;
        acc0 += w * hp[lane];            // coalesced 256B gather
        if (lane < 4) acc1 += w * hp[64 + lane];
    }
    float self = dd * dd;
    const float* hd = h1 + (long long)d * HIDP;
    float v0 = b1[lane] + self * hd[lane] + dd * acc0;
    out1[(long long)d * HIDP + lane] = v0 > 0.f ? v0 : 0.01f * v0;
    if (lane < 4) {
        int j = 64 + lane;
        float bb = (j < HID) ? b1[j] : 0.f;
        float v1 = bb + self * hd[j] + dd * acc1;   // j=67: all zero -> stays 0
        out1[(long long)d * HIDP + j] = v1 > 0.f ? v1 : 0.01f * v1;
    }
}

// ---------------- GEMM2: h2[N,8] = out1[N,68] @ W2[67,7] (no bias, no act) ----

__global__ __launch_bounds__(256) void k_gemm2(const float* __restrict__ out1,
                                               const float* __restrict__ W2,
                                               float* __restrict__ h2, int N) {
    __shared__ float w2s[HIDP][NCP];
    int t = threadIdx.x;
    for (int idx = t; idx < HIDP * NCP; idx += 256) {
        int k = idx >> 3, j = idx & 7;
        w2s[k][j] = (k < HID && j < NC) ? W2[k * NC + j] : 0.f;
    }
    __syncthreads();
    int i = blockIdx.x * 256 + t;
    if (i >= N) return;
    const float4* row = (const float4*)(out1 + (long long)i * HIDP);
    float acc[NC];
#pragma unroll
    for (int j = 0; j < NC; j++) acc[j] = 0.f;
#pragma unroll
    for (int kq = 0; kq < 17; kq++) {
        float4 v = row[kq];
        float av[4] = {v.x, v.y, v.z, v.w};
#pragma unroll
        for (int c = 0; c < 4; c++) {
            int k = kq * 4 + c;
            float a = av[c];
#pragma unroll
            for (int j = 0; j < NC; j++) acc[j] = fmaf(a, w2s[k][j], acc[j]);
        }
    }
    float* hp = h2 + (long long)i * NCP;
#pragma unroll
    for (int j = 0; j < NC; j++) hp[j] = acc[j];
    hp[NC] = 0.f;   // pad
}

// ---------------- agg2: out2 = b2 + dinv_d^2*h2_d + dinv_d * sum_e dinv_s*h2_s ----

__global__ __launch_bounds__(256) void k_agg2(const float* __restrict__ h2,
                                              const int* __restrict__ rowptr,
                                              const int* __restrict__ csrs,
                                              const float* __restrict__ dinv,
                                              const float* __restrict__ b2,
                                              float* __restrict__ out2, int N) {
    int gid = blockIdx.x * 256 + threadIdx.x;
    int d = gid >> 3;       // 8 threads per node
    int j = gid & 7;
    if (d >= N) return;
    int start = rowptr[d], end = rowptr[d + 1];
    float dd = dinv[d];
    float acc = 0.f;
    for (int e = start; e < end; e++) {
        int s = csrs[e];
        acc += dinv[s] * h2[(long long)s * NCP + j];
    }
    float bb = (j < NC) ? b2[j] : 0.f;
    float v = bb + dd * dd * h2[(long long)d * NCP + j] + dd * acc;
    out2[(long long)d * NCP + j] = v;
}

// ---------------- log_softmax over 7 classes ----------------

__global__ void k_lsm(const float* __restrict__ out2, float* __restrict__ out, int N) {
    int i = blockIdx.x * 256 + threadIdx.x;
    if (i >= N) return;
    const float* z = out2 + (long long)i * NCP;
    float zv[NC];
    float m = -1e30f;
#pragma unroll
    for (int j = 0; j < NC; j++) { zv[j] = z[j]; m = fmaxf(m, zv[j]); }
    float ssum = 0.f;
#pragma unroll
    for (int j = 0; j < NC; j++) ssum += __expf(zv[j] - m);
    float l = __logf(ssum);
#pragma unroll
    for (int j = 0; j < NC; j++) out[(long long)i * NC + j] = zv[j] - m - l;
}

// ---------------- launch ----------------

extern "C" void kernel_launch(void* const* d_in, const int* in_sizes, int n_in,
                              void* d_out, int out_size, void* d_ws, size_t ws_size,
                              hipStream_t stream) {
    const float* x  = (const float*)d_in[0];
    const int*   ei = (const int*)d_in[1];
    const float* W1 = (const float*)d_in[2];
    const float* b1 = (const float*)d_in[3];
    const float* W2 = (const float*)d_in[4];
    const float* b2 = (const float*)d_in[5];
    float* out = (float*)d_out;

    int N = in_sizes[0] / FIN;   // 100000
    int E = in_sizes[1] / 2;     // 3200000

    // workspace carve-up (4-byte words, 256B-aligned chunks)
    size_t o = 0;
    auto alloc = [&](size_t words) { size_t r = o; o += words; o = (o + 63) & ~(size_t)63; return r; };
    size_t o_dinv   = alloc((size_t)N);
    size_t o_cnt    = alloc((size_t)N);
    size_t o_rowptr = alloc((size_t)N + 1);
    size_t o_cursor = alloc((size_t)N);
    size_t o_bsum   = alloc(1024);
    size_t o_csrs   = alloc((size_t)E);
    size_t o_h1     = alloc((size_t)N * HIDP);
    size_t o_out1   = alloc((size_t)N * HIDP);
    size_t o_h2     = alloc((size_t)N * NCP);
    size_t o_out2   = alloc((size_t)N * NCP);

    float* wsf = (float*)d_ws;
    int*   wsi = (int*)d_ws;
    float* dinv   = wsf + o_dinv;
    int*   cnt    = wsi + o_cnt;
    int*   rowptr = wsi + o_rowptr;
    int*   cursor = wsi + o_cursor;
    int*   bsum   = wsi + o_bsum;
    int*   csrs   = wsi + o_csrs;
    float* h1     = wsf + o_h1;
    float* o1     = wsf + o_out1;
    float* h2     = wsf + o_h2;
    float* o2     = wsf + o_out2;

    int nb = (N + 255) / 256;        // 391
    int eb = (E + 255) / 256;        // 12500

    k_zero <<<nb, 256, 0, stream>>>(cnt, N);
    k_count<<<eb, 256, 0, stream>>>(ei + E, cnt, E);
    k_bsum <<<nb, 256, 0, stream>>>(cnt, bsum, N);
    k_scanb<<<1, 512, 0, stream>>>(bsum, nb);
    k_scan3<<<nb, 256, 0, stream>>>(cnt, bsum, rowptr, cursor, dinv, N, E);
    k_fill <<<eb, 256, 0, stream>>>(ei, cursor, csrs, E);

    k_gemm1<<<nb, 256, 0, stream>>>(x, W1, h1, N);
    k_agg1 <<<(N + 3) / 4, 256, 0, stream>>>(h1, rowptr, csrs, dinv, b1, o1, N);
    k_gemm2<<<nb, 256, 0, stream>>>(o1, W2, h2, N);
    k_agg2 <<<((size_t)N * NCP + 255) / 256, 256, 0, stream>>>(h2, rowptr, csrs, dinv, b2, o2, N);
    k_lsm  <<<nb, 256, 0, stream>>>(o2, out, N);
}

// Round 2
// 1592.330 us; speedup vs baseline: 2.1134x; 2.1134x over previous
//
#include <hip/hip_runtime.h>
#include <math.h>

#define FIN  1433
#define HID  67
#define HIDP 68
#define NC   7
#define NCP  8

#define BK     32
#define KTILES 45            // ceil(1433/32)
#define KPAD   (KTILES*BK)   // 1440
#define COLP   80            // 5 tiles of 16 (67 real cols, rest zero)

typedef __attribute__((ext_vector_type(8))) short short8;
typedef __attribute__((ext_vector_type(4))) float floatx4;

static __device__ inline unsigned short f2bf(float f) {
    unsigned int u = __float_as_uint(f);
    unsigned int r = (u + 0x7fffu + ((u >> 16) & 1u)) >> 16;   // RNE
    return (unsigned short)r;
}

// ---------------- CSR build ----------------

__global__ void k_zero(int* __restrict__ cnt, int N) {
    int i = blockIdx.x * 256 + threadIdx.x;
    if (i < N) cnt[i] = 0;
}

__global__ void k_count(const int* __restrict__ dst, int* __restrict__ cnt, int E) {
    int e = blockIdx.x * 256 + threadIdx.x;
    if (e < E) atomicAdd(&cnt[dst[e]], 1);
}

__global__ void k_bsum(const int* __restrict__ cnt, int* __restrict__ bsum, int N) {
    __shared__ int s[256];
    int t = threadIdx.x;
    int i = blockIdx.x * 256 + t;
    s[t] = (i < N) ? cnt[i] : 0;
    __syncthreads();
    for (int o = 128; o > 0; o >>= 1) {
        if (t < o) s[t] += s[t + o];
        __syncthreads();
    }
    if (t == 0) bsum[blockIdx.x] = s[0];
}

// exclusive scan of block sums; nb <= 512
__global__ void k_scanb(int* __restrict__ bsum, int nb) {
    __shared__ int s[512];
    int t = threadIdx.x;
    int v = (t < nb) ? bsum[t] : 0;
    s[t] = v;
    __syncthreads();
    for (int o = 1; o < 512; o <<= 1) {
        int tmp = (t >= o) ? s[t - o] : 0;
        __syncthreads();
        s[t] += tmp;
        __syncthreads();
    }
    if (t < nb) bsum[t] = s[t] - v;  // exclusive
}

__global__ void k_scan3(const int* __restrict__ cnt, const int* __restrict__ bsum,
                        int* __restrict__ rowptr, int* __restrict__ cursor,
                        float* __restrict__ dinv, int N, int E) {
    __shared__ int s[256];
    int t = threadIdx.x;
    int i = blockIdx.x * 256 + t;
    int v = (i < N) ? cnt[i] : 0;
    s[t] = v;
    __syncthreads();
    for (int o = 1; o < 256; o <<= 1) {
        int tmp = (t >= o) ? s[t - o] : 0;
        __syncthreads();
        s[t] += tmp;
        __syncthreads();
    }
    if (i < N) {
        int start = bsum[blockIdx.x] + s[t] - v;  // exclusive global prefix
        rowptr[i] = start;
        cursor[i] = start;
        dinv[i]   = rsqrtf((float)(v + 1));       // +1 self loop
    }
    if (i == 0) rowptr[N] = E;
}

__global__ void k_fill(const int* __restrict__ ei, int* __restrict__ cursor,
                       int* __restrict__ csrs, int E) {
    int e = blockIdx.x * 256 + threadIdx.x;
    if (e < E) {
        int s = ei[e];          // source
        int d = ei[E + e];      // target
        int pos = atomicAdd(&cursor[d], 1);
        csrs[pos] = s;
    }
}

// ---------------- W1 -> bf16, padded, col-major-by-col: Wt[col][k] ----------------

__global__ void k_wcvt(const float* __restrict__ W1, unsigned short* __restrict__ Wt) {
    int idx = blockIdx.x * 256 + threadIdx.x;
    if (idx >= COLP * KPAD) return;
    int col = idx / KPAD;
    int k   = idx - col * KPAD;
    float v = (col < HID && k < FIN) ? W1[k * HID + col] : 0.f;
    Wt[idx] = f2bf(v);
}

// ---------------- GEMM1 (MFMA bf16): h1[N,68] = x[N,1433] @ W1 ----------------
// block: 64 rows x 80 cols, 4 waves; wave w = 16-row strip, 5 col-tiles of 16.

__global__ __launch_bounds__(256) void k_gemm1(const float* __restrict__ x,
                                               const unsigned short* __restrict__ Wt,
                                               float* __restrict__ h1, int N) {
    __shared__ unsigned short As[64][BK];    // [row][k]  4 KB
    __shared__ unsigned short Bs[COLP][BK];  // [col][k]  5 KB
    int t    = threadIdx.x;
    int lane = t & 63;
    int w    = t >> 6;        // wave id = row strip
    int lm   = lane & 15;
    int lq   = lane >> 4;
    int row0 = blockIdx.x * 64;

    floatx4 acc[5];
#pragma unroll
    for (int j = 0; j < 5; j++) acc[j] = (floatx4){0.f, 0.f, 0.f, 0.f};

    for (int kt = 0; kt < KPAD; kt += BK) {
        // stage A: 64 rows x 32 k, fp32 -> bf16 (row stride 1433 is odd -> scalar loads)
#pragma unroll
        for (int q = 0; q < 4; q++) {
            int idx2 = q * 256 + t;     // float-pair index, 1024 total
            int r  = idx2 >> 4;
            int kp = idx2 & 15;
            int grow = row0 + r;
            int k0 = kt + kp * 2;
            float v0 = 0.f, v1 = 0.f;
            if (grow < N && k0 < FIN) {
                const float* xp = x + (long long)grow * FIN + k0;
                v0 = xp[0];
                if (k0 + 1 < FIN) v1 = xp[1];
            }
            unsigned int pk = (unsigned int)f2bf(v0) | ((unsigned int)f2bf(v1) << 16);
            *(unsigned int*)&As[r][kp * 2] = pk;
        }
        // stage B from Wt (already bf16, contiguous per col)
#pragma unroll
        for (int q = 0; q < 5; q++) {
            int idx = q * 256 + t;      // u32 index, 1280 total
            int col = idx >> 4;
            int kp  = idx & 15;
            unsigned int v = *(const unsigned int*)&Wt[col * KPAD + kt + kp * 2];
            *(unsigned int*)&Bs[col][kp * 2] = v;
        }
        __syncthreads();
        // A frag: A[m=lane&15][k=lq*8+j], contiguous 8 bf16 -> one b128
        short8 a = *(const short8*)&As[w * 16 + lm][lq * 8];
#pragma unroll
        for (int j = 0; j < 5; j++) {
            short8 b = *(const short8*)&Bs[j * 16 + lm][lq * 8];
            acc[j] = __builtin_amdgcn_mfma_f32_16x16x32_bf16(a, b, acc[j], 0, 0, 0);
        }
        __syncthreads();
    }
    // epilogue: C/D layout col=lane&15, row=lq*4+i
#pragma unroll
    for (int j = 0; j < 5; j++) {
        int col = j * 16 + lm;
        if (col < HIDP) {
#pragma unroll
            for (int i = 0; i < 4; i++) {
                int row = row0 + w * 16 + lq * 4 + i;
                if (row < N) h1[(long long)row * HIDP + col] = acc[j][i];
            }
        }
    }
}

// ---------------- agg1: out1 = lrelu(b1 + dinv_d^2*h1_d + dinv_d * sum_e dinv_s*h1_s) ----

__global__ __launch_bounds__(256) void k_agg1(const float* __restrict__ h1,
                                              const int* __restrict__ rowptr,
                                              const int* __restrict__ csrs,
                                              const float* __restrict__ dinv,
                                              const float* __restrict__ b1,
                                              float* __restrict__ out1, int N) {
    int lane = threadIdx.x & 63;
    int d = blockIdx.x * 4 + (threadIdx.x >> 6);   // wave per node
    if (d >= N) return;
    int start = rowptr[d];
    int end   = rowptr[d + 1];
    float dd = dinv[d];
    float acc0 = 0.f, acc1 = 0.f;
    for (int e = start; e < end; e++) {
        int s = csrs[e];                 // wave-uniform -> broadcast load
        float w = dinv[s];
        const float* hp = h1 + (long long)s * HIDP;
        acc0 += w * hp[lane];            // coalesced 256B gather
        if (lane < 4) acc1 += w * hp[64 + lane];
    }
    float self = dd * dd;
    const float* hd = h1 + (long long)d * HIDP;
    float v0 = b1[lane] + self * hd[lane] + dd * acc0;
    out1[(long long)d * HIDP + lane] = v0 > 0.f ? v0 : 0.01f * v0;
    if (lane < 4) {
        int j = 64 + lane;
        float bb = (j < HID) ? b1[j] : 0.f;
        float v1 = bb + self * hd[j] + dd * acc1;   // j=67: all zero -> stays 0
        out1[(long long)d * HIDP + j] = v1 > 0.f ? v1 : 0.01f * v1;
    }
}

// ---------------- GEMM2: h2[N,8] = out1[N,68] @ W2[67,7] ----------------

__global__ __launch_bounds__(256) void k_gemm2(const float* __restrict__ out1,
                                               const float* __restrict__ W2,
                                               float* __restrict__ h2, int N) {
    __shared__ float w2s[HIDP][NCP];
    int t = threadIdx.x;
    for (int idx = t; idx < HIDP * NCP; idx += 256) {
        int k = idx >> 3, j = idx & 7;
        w2s[k][j] = (k < HID && j < NC) ? W2[k * NC + j] : 0.f;
    }
    __syncthreads();
    int i = blockIdx.x * 256 + t;
    if (i >= N) return;
    const float4* row = (const float4*)(out1 + (long long)i * HIDP);
    float acc[NC];
#pragma unroll
    for (int j = 0; j < NC; j++) acc[j] = 0.f;
#pragma unroll
    for (int kq = 0; kq < 17; kq++) {
        float4 v = row[kq];
        float av[4] = {v.x, v.y, v.z, v.w};
#pragma unroll
        for (int c = 0; c < 4; c++) {
            int k = kq * 4 + c;
            float a = av[c];
#pragma unroll
            for (int j = 0; j < NC; j++) acc[j] = fmaf(a, w2s[k][j], acc[j]);
        }
    }
    float* hp = h2 + (long long)i * NCP;
#pragma unroll
    for (int j = 0; j < NC; j++) hp[j] = acc[j];
    hp[NC] = 0.f;   // pad
}

// ---------------- agg2 ----------------

__global__ __launch_bounds__(256) void k_agg2(const float* __restrict__ h2,
                                              const int* __restrict__ rowptr,
                                              const int* __restrict__ csrs,
                                              const float* __restrict__ dinv,
                                              const float* __restrict__ b2,
                                              float* __restrict__ out2, int N) {
    int gid = blockIdx.x * 256 + threadIdx.x;
    int d = gid >> 3;       // 8 threads per node
    int j = gid & 7;
    if (d >= N) return;
    int start = rowptr[d], end = rowptr[d + 1];
    float dd = dinv[d];
    float acc = 0.f;
    for (int e = start; e < end; e++) {
        int s = csrs[e];
        acc += dinv[s] * h2[(long long)s * NCP + j];
    }
    float bb = (j < NC) ? b2[j] : 0.f;
    float v = bb + dd * dd * h2[(long long)d * NCP + j] + dd * acc;
    out2[(long long)d * NCP + j] = v;
}

// ---------------- log_softmax over 7 classes ----------------

__global__ void k_lsm(const float* __restrict__ out2, float* __restrict__ out, int N) {
    int i = blockIdx.x * 256 + threadIdx.x;
    if (i >= N) return;
    const float* z = out2 + (long long)i * NCP;
    float zv[NC];
    float m = -1e30f;
#pragma unroll
    for (int j = 0; j < NC; j++) { zv[j] = z[j]; m = fmaxf(m, zv[j]); }
    float ssum = 0.f;
#pragma unroll
    for (int j = 0; j < NC; j++) ssum += __expf(zv[j] - m);
    float l = __logf(ssum);
#pragma unroll
    for (int j = 0; j < NC; j++) out[(long long)i * NC + j] = zv[j] - m - l;
}

// ---------------- launch ----------------

extern "C" void kernel_launch(void* const* d_in, const int* in_sizes, int n_in,
                              void* d_out, int out_size, void* d_ws, size_t ws_size,
                              hipStream_t stream) {
    const float* x  = (const float*)d_in[0];
    const int*   ei = (const int*)d_in[1];
    const float* W1 = (const float*)d_in[2];
    const float* b1 = (const float*)d_in[3];
    const float* W2 = (const float*)d_in[4];
    const float* b2 = (const float*)d_in[5];
    float* out = (float*)d_out;

    int N = in_sizes[0] / FIN;   // 100000
    int E = in_sizes[1] / 2;     // 3200000

    size_t o = 0;
    auto alloc = [&](size_t words) { size_t r = o; o += words; o = (o + 63) & ~(size_t)63; return r; };
    size_t o_dinv   = alloc((size_t)N);
    size_t o_cnt    = alloc((size_t)N);
    size_t o_rowptr = alloc((size_t)N + 1);
    size_t o_cursor = alloc((size_t)N);
    size_t o_bsum   = alloc(1024);
    size_t o_csrs   = alloc((size_t)E);
    size_t o_wt     = alloc((size_t)COLP * KPAD / 2);   // bf16, u32 words
    size_t o_h1     = alloc((size_t)N * HIDP);
    size_t o_out1   = alloc((size_t)N * HIDP);
    size_t o_h2     = alloc((size_t)N * NCP);
    size_t o_out2   = alloc((size_t)N * NCP);

    float* wsf = (float*)d_ws;
    int*   wsi = (int*)d_ws;
    float* dinv   = wsf + o_dinv;
    int*   cnt    = wsi + o_cnt;
    int*   rowptr = wsi + o_rowptr;
    int*   cursor = wsi + o_cursor;
    int*   bsum   = wsi + o_bsum;
    int*   csrs   = wsi + o_csrs;
    unsigned short* Wt = (unsigned short*)(wsi + o_wt);
    float* h1     = wsf + o_h1;
    float* o1     = wsf + o_out1;
    float* h2     = wsf + o_h2;
    float* o2     = wsf + o_out2;

    int nb = (N + 255) / 256;        // 391
    int eb = (E + 255) / 256;        // 12500
    int gb = (N + 63) / 64;          // 1563 blocks for gemm1

    k_zero <<<nb, 256, 0, stream>>>(cnt, N);
    k_count<<<eb, 256, 0, stream>>>(ei + E, cnt, E);
    k_bsum <<<nb, 256, 0, stream>>>(cnt, bsum, N);
    k_scanb<<<1, 512, 0, stream>>>(bsum, nb);
    k_scan3<<<nb, 256, 0, stream>>>(cnt, bsum, rowptr, cursor, dinv, N, E);
    k_fill <<<eb, 256, 0, stream>>>(ei, cursor, csrs, E);

    k_wcvt <<<(COLP * KPAD + 255) / 256, 256, 0, stream>>>(W1, Wt);
    k_gemm1<<<gb, 256, 0, stream>>>(x, Wt, h1, N);
    k_agg1 <<<(N + 3) / 4, 256, 0, stream>>>(h1, rowptr, csrs, dinv, b1, o1, N);
    k_gemm2<<<nb, 256, 0, stream>>>(o1, W2, h2, N);
    k_agg2 <<<((size_t)N * NCP + 255) / 256, 256, 0, stream>>>(h2, rowptr, csrs, dinv, b2, o2, N);
    k_lsm  <<<nb, 256, 0, stream>>>(o2, out, N);
}